// Round 8
// baseline (95.130 us; speedup 1.0000x reference)
//
#include <hip/hip_runtime.h>
#include <math.h>

#define NB 8
#define ND 128
#define NT 2048
#define NF 1025
#define NYY 256
#define NXX 256

#define SPEC_BYTES 8396800          /* 8*128*1025*8 */
#define BAND_PART_BYTES 2097152     /* 8*128*256*8 (fp32 bandS) */
#define BANDH_PART_BYTES 1048576    /* 8*128*256*4 (bf16x2 band part) */
#define PART_OFF   1024
#define SPECT_OFF  8192
#define SF_OFF     (SPECT_OFF + SPEC_BYTES)            /* 8,404,992 */
#define BAND_OFF   (SF_OFF + SPEC_BYTES)               /* 16,801,792 */

// ---------------- kernel 1a: per-chunk sums for standardization ----------------
__global__ __launch_bounds__(256) void fk_part_sums(const float* __restrict__ sino,
                                                    double2* __restrict__ part) {
  const int c = blockIdx.x;   // 0..31 chunk
  const int b = blockIdx.y;   // 0..7 batch
  const int tid = threadIdx.x;
  const int chunk = ND * NT / 32;  // 8192
  const float* p = sino + (size_t)b * ND * NT + (size_t)c * chunk;
  double s = 0.0, ss = 0.0;
  for (int i = tid; i < chunk; i += 256) {
    float v = p[i];
    s += (double)v;
    ss += (double)v * (double)v;
  }
  __shared__ double shs[256];
  __shared__ double shq[256];
  shs[tid] = s; shq[tid] = ss;
  __syncthreads();
  for (int o = 128; o > 0; o >>= 1) {
    if (tid < o) { shs[tid] += shs[tid + o]; shq[tid] += shq[tid + o]; }
    __syncthreads();
  }
  if (tid == 0) part[b * 32 + c] = make_double2(shs[0], shq[0]);
}

// ---------------- kernel 1b: finalize 1/sqrt(var+eps) ----------------
__global__ void fk_scale_k(const double2* __restrict__ part, float* __restrict__ scale) {
  int t = threadIdx.x;
  if (t < NB) {
    double s = 0.0, ss = 0.0;
    for (int c = 0; c < 32; ++c) { double2 v = part[t * 32 + c]; s += v.x; ss += v.y; }
    const double n = (double)(ND * NT);
    double mean = s / n;
    double var = ss / n - mean * mean;
    scale[t] = (float)(1.0 / sqrt(var + 1.1920928955078125e-7));
  }
}

// ---------------- kernel 2: real 2048-pt rfft via 1024-pt complex FFT + untangle ----
__global__ __launch_bounds__(256) void fk_tfft(const float* __restrict__ sino,
                                               float2* __restrict__ specT) {
  const int row = blockIdx.x;      // b*ND + d
  const int d = row & (ND - 1);
  const int tid = threadIdx.x;
  __shared__ float2 bufA[1024];
  __shared__ float2 bufB[1024];
  const float ap = (float)(0.5 - 0.5 * cos(6.283185307179586 * (double)d / 127.0));
  const float2* in = (const float2*)(sino + (size_t)row * NT);   // z[n] = x[2n] + i x[2n+1]
  for (int i = tid; i < 1024; i += 256) {
    float2 v = in[i];
    bufA[i] = make_float2(v.x * ap, v.y * ap);
  }
  __syncthreads();
  float2* src = bufA;
  float2* dst = bufB;
  for (int p = 1; p <= 512; p <<= 1) {
    #pragma unroll
    for (int it = 0; it < 2; ++it) {
      int i = tid + it * 256;
      int k = i & (p - 1);
      float2 u = src[i];
      float2 v = src[i + 512];
      float ang = -3.14159265358979323846f * ((float)k / (float)p);
      float sn, cs; __sincosf(ang, &sn, &cs);
      float2 vw = make_float2(v.x * cs - v.y * sn, v.x * sn + v.y * cs);
      int j = ((i - k) << 1) + k;
      dst[j]     = make_float2(u.x + vw.x, u.y + vw.y);
      dst[j + p] = make_float2(u.x - vw.x, u.y - vw.y);
    }
    __syncthreads();
    float2* t = src; src = dst; dst = t;
  }
  // src = Z[0..1023]; untangle to rfft X[0..1024]
  float2* out = specT + (size_t)row * NF;
  for (int k = tid; k < 1024; k += 256) {
    float2 zk = src[k];
    float2 zc = src[(1024 - k) & 1023]; zc.y = -zc.y;          // conj
    float2 xe = make_float2(0.5f * (zk.x + zc.x), 0.5f * (zk.y + zc.y));
    float ax = zk.x - zc.x, ay = zk.y - zc.y;
    float2 xo = make_float2(0.5f * ay, -0.5f * ax);            // (Z - Zc)/(2i)
    float ang = -3.14159265358979323846f * ((float)k / 1024.0f);
    float sn, cs; __sincosf(ang, &sn, &cs);
    out[k] = make_float2(xe.x + cs * xo.x - sn * xo.y,
                         xe.y + cs * xo.y + sn * xo.x);
  }
  if (tid == 0) {
    float2 z0 = src[0];
    out[1024] = make_float2(z0.x - z0.y, 0.0f);
  }
}

// ---------------- kernel 3: detector FFT (128-pt) + prop_mask*fw ----------------
__global__ __launch_bounds__(256) void fk_dfft(const float2* __restrict__ specT,
                                               float2* __restrict__ sf) {
  const int b = blockIdx.y;
  const int f0 = blockIdx.x * 4;
  const int sub = threadIdx.x >> 6;   // 0..3 (which f)
  const int i = threadIdx.x & 63;     // butterfly index
  const int f = f0 + sub;
  const bool valid = (f < NF);
  __shared__ float2 A[4][128];
  __shared__ float2 Bf[4][128];
  if (valid) {
    const float2* col = specT + ((size_t)b * ND) * NF + f;
    A[sub][i]      = col[(size_t)i * NF];
    A[sub][i + 64] = col[(size_t)(i + 64) * NF];
  }
  __syncthreads();
  float2 (*src)[128] = A;
  float2 (*dst)[128] = Bf;
  for (int p = 1; p <= 64; p <<= 1) {
    if (valid) {
      int k = i & (p - 1);
      float2 u = src[sub][i];
      float2 v = src[sub][i + 64];
      float ang = -3.14159265358979323846f * ((float)k / (float)p);
      float sn, cs; __sincosf(ang, &sn, &cs);
      float2 vw = make_float2(v.x * cs - v.y * sn, v.x * sn + v.y * cs);
      int j = ((i - k) << 1) + k;
      dst[sub][j]     = make_float2(u.x + vw.x, u.y + vw.y);
      dst[sub][j + p] = make_float2(u.x - vw.x, u.y - vw.y);
    }
    __syncthreads();
    float2 (*t)[128] = src; src = dst; dst = t;
  }
  if (valid) {
    const float fwv = (f == 0 || f == NF - 1) ? 1.0f : 2.0f;
    double freqd = (double)f / 5.12e-5;
    float omega = (float)(freqd * 6.283185307179586);
    float woc = omega / 1540.0f;
    float woc2 = __fmul_rn(woc, woc);
    #pragma unroll
    for (int h = 0; h < 2; ++h) {
      int kd = i + h * 64;
      int kt = kd < 64 ? kd : kd - 128;
      float kxv = (float)(6.283185307179586 * ((double)kt / 0.0384));
      float kzsq = __fsub_rn(woc2, __fmul_rn(kxv, kxv));
      float m = (kzsq > 0.0f) ? fwv : 0.0f;
      float2 v = src[sub][kd];
      sf[((size_t)(b * ND + kd)) * NF + f] = make_float2(v.x * m, v.y * m);
    }
  }
}

__device__ __forceinline__ unsigned int bf16rne(float x) {
  unsigned int u = __float_as_uint(x);
  return (u + 0x7fffu + ((u >> 16) & 1u)) >> 16;
}

// ---------------- kernel 4: band_h[part][b][d][y] (bf16x2) = sum_f sf*exp(i*kz*y) ----
// Wave w owns d = dblk*4+w; each thread owns 4 y (lane+64i). Each uniform
// ds_read_b64 feeds 16 FMAs -> LDS pipe no longer the wall.
__global__ __launch_bounds__(256) void fk_band(const float2* __restrict__ sf,
                                               unsigned int* __restrict__ bandh,
                                               int flen_base, int fpad) {
  const int dblk = blockIdx.x;   // 0..31
  const int part = blockIdx.y;   // 0..FPART-1
  const int f0 = part * flen_base;
  const int flen = min(flen_base, NF - f0);
  const int tid = threadIdx.x;
  const int w = tid >> 6, l = tid & 63;
  const int d = dblk * 4 + w;

  extern __shared__ float lds[];
  float2* sfs = (float2*)lds;            // [32 rows][fpad]  row = w*8+b
  float*  kzs = lds + 64 * fpad;         // [4][fpad]

  // stage sf rows (8-thread runs per row, coalesced 64B chunks)
  {
    const int row = tid >> 3;            // 0..31
    const int wr = row >> 3, br = row & 7;
    const int dr = dblk * 4 + wr;
    const float2* srcp = sf + ((size_t)(br * ND + dr)) * NF + f0;
    for (int ff = tid & 7; ff < fpad; ff += 8)
      sfs[row * fpad + ff] = (ff < flen) ? srcp[ff] : make_float2(0.f, 0.f);
  }
  // stage kz per wave-d
  for (int e = tid; e < 4 * fpad; e += 256) {
    const int wk = e / fpad, ff = e - wk * fpad;
    float kzv = 0.f;
    if (ff < flen) {
      int dk = dblk * 4 + wk;
      int kt = dk < 64 ? dk : dk - 128;
      float kxv = (float)(6.283185307179586 * ((double)kt / 0.0384));
      float kx2 = __fmul_rn(kxv, kxv);
      int f = f0 + ff;
      double freqd = (double)f / 5.12e-5;
      float omega = (float)(freqd * 6.283185307179586);
      float woc = omega / 1540.0f;
      float kzsq = __fsub_rn(__fmul_rn(woc, woc), kx2);
      kzv = (kzsq > 0.0f) ? sqrtf(kzsq) : 0.0f;
    }
    kzs[e] = kzv;
  }
  __syncthreads();

  float yv[4];
  #pragma unroll
  for (int i = 0; i < 4; ++i)
    yv[i] = (float)(1.0e-3 + (double)(l + 64 * i) * 1.5e-4);

  float2 acc[8][4];
  #pragma unroll
  for (int b = 0; b < 8; ++b)
    #pragma unroll
    for (int i = 0; i < 4; ++i) acc[b][i] = make_float2(0.f, 0.f);

  const float* kzw = kzs + w * fpad;
  const float2* rows = sfs + (w * 8) * fpad;
  const int nm = fpad >> 1;
  for (int m = 0; m < nm; ++m) {
    const float k0 = kzw[2 * m];
    const float k1 = kzw[2 * m + 1];
    float cs[2][4], sn[2][4];
    #pragma unroll
    for (int i = 0; i < 4; ++i) {
      __sincosf(k0 * yv[i], &sn[0][i], &cs[0][i]);
      __sincosf(k1 * yv[i], &sn[1][i], &cs[1][i]);
    }
    #pragma unroll
    for (int u = 0; u < 2; ++u) {
      #pragma unroll
      for (int b = 0; b < 8; ++b) {
        float2 p = rows[b * fpad + 2 * m + u];   // uniform broadcast b64
        #pragma unroll
        for (int i = 0; i < 4; ++i) {
          acc[b][i].x = fmaf(p.x, cs[u][i], fmaf(-p.y, sn[u][i], acc[b][i].x));
          acc[b][i].y = fmaf(p.x, sn[u][i], fmaf( p.y, cs[u][i], acc[b][i].y));
        }
      }
    }
  }

  unsigned int* outp = bandh + (size_t)part * (NB * ND * NYY);
  #pragma unroll
  for (int b = 0; b < 8; ++b)
    #pragma unroll
    for (int i = 0; i < 4; ++i) {
      unsigned int pk = bf16rne(acc[b][i].x) | (bf16rne(acc[b][i].y) << 16);
      outp[((size_t)(b * ND + d)) * NYY + l + 64 * i] = pk;   // coalesced per (b,i)
    }
}

// ---------------- kernel 4b: bandS[b][d][y] (fp32) = sum_part band_h ----------------
__global__ __launch_bounds__(256) void fk_sum(const unsigned int* __restrict__ bandh,
                                              float2* __restrict__ bandS, int nparts) {
  const int n = blockIdx.x * 256 + threadIdx.x;   // [b][d][y], coalesced both sides
  float sx = 0.f, sy = 0.f;
  for (int p = 0; p < nparts; ++p) {
    unsigned int u = bandh[(size_t)p * (NB * ND * NYY) + n];
    sx += __uint_as_float(u << 16);
    sy += __uint_as_float(u & 0xffff0000u);
  }
  bandS[n] = make_float2(sx, sy);
}

// ---------------- kernel 5: lateral transform as 256-pt inverse FFT + magnitude ----
__global__ __launch_bounds__(256) void fk_img(const float2* __restrict__ bandS,
                                              const float* __restrict__ scale,
                                              float* __restrict__ out, float inv_norm) {
  const int y = blockIdx.x;
  const int b = blockIdx.y;
  const int tid = threadIdx.x;
  __shared__ float2 A[256];
  __shared__ float2 Bb[256];
  {
    float2 v = make_float2(0.f, 0.f);
    if (tid < 64)        v = bandS[((size_t)(b * ND + tid)) * NYY + y];        // bin d
    else if (tid >= 192) v = bandS[((size_t)(b * ND + tid - 128)) * NYY + y];  // bin d+128
    A[tid] = v;
  }
  __syncthreads();
  float2* src = A;
  float2* dst = Bb;
  for (int p = 1; p <= 128; p <<= 1) {
    if (tid < 128) {
      int i = tid;
      int k = i & (p - 1);
      float2 u = src[i];
      float2 v = src[i + 128];
      float ang = 3.14159265358979323846f * ((float)k / (float)p);   // +: inverse
      float sn, cs; __sincosf(ang, &sn, &cs);
      float2 vw = make_float2(v.x * cs - v.y * sn, v.x * sn + v.y * cs);
      int j = ((i - k) << 1) + k;
      dst[j]     = make_float2(u.x + vw.x, u.y + vw.y);
      dst[j + p] = make_float2(u.x - vw.x, u.y - vw.y);
    }
    __syncthreads();
    float2* t = src; src = dst; dst = t;
  }
  float2 r = src[tid];
  float mag = sqrtf(r.x * r.x + r.y * r.y);
  out[((size_t)b * NYY + y) * NXX + tid] = mag * scale[b] * inv_norm;
}

extern "C" void kernel_launch(void* const* d_in, const int* in_sizes, int n_in,
                              void* d_out, int out_size, void* d_ws, size_t ws_size,
                              hipStream_t stream) {
  const float* sino = (const float*)d_in[0];
  float* out = (float*)d_out;
  char* ws = (char*)d_ws;

  float*        scale = (float*)(ws + 0);
  double2*      part  = (double2*)(ws + PART_OFF);
  float2*       specT = (float2*)(ws + SPECT_OFF);
  float2*       sf    = (float2*)(ws + SF_OFF);
  unsigned int* bandh = (unsigned int*)(ws + BAND_OFF);

  // f-partition tier from ws_size (deterministic)
  int FPART = 8;
  if (ws_size >= (size_t)BAND_OFF + 47u * BANDH_PART_BYTES + BAND_PART_BYTES) FPART = 47;
  else if (ws_size >= (size_t)BAND_OFF + 16u * BANDH_PART_BYTES + BAND_PART_BYTES) FPART = 16;
  const int flen_base = (NF + FPART - 1) / FPART;     // 22 / 65 / 129
  const int fpad = (flen_base + 1) & ~1;              // 22 / 66 / 130
  const size_t band_lds = (size_t)fpad * 272;         // 32*8B + 4*4B per ff
  float2* bandS = (float2*)(ws + BAND_OFF + (size_t)FPART * BANDH_PART_BYTES);

  double apod_sum = 0.0;
  for (int n = 0; n < ND; ++n) apod_sum += 0.5 - 0.5 * cos(6.283185307179586 * (double)n / 127.0);
  const float inv_norm = (float)(1.0 / (apod_sum * 2048.0));

  fk_part_sums<<<dim3(32, NB), 256, 0, stream>>>(sino, part);
  fk_scale_k <<<1, 64, 0, stream>>>(part, scale);
  fk_tfft    <<<NB * ND, 256, 0, stream>>>(sino, specT);
  fk_dfft    <<<dim3((NF + 3) / 4, NB), 256, 0, stream>>>(specT, sf);
  fk_band    <<<dim3(32, FPART), 256, band_lds, stream>>>(sf, bandh, flen_base, fpad);
  fk_sum     <<<NB * ND * NYY / 256, 256, 0, stream>>>(bandh, bandS, FPART);
  fk_img     <<<dim3(NYY, NB), 256, 0, stream>>>(bandS, scale, out, inv_norm);
}

// Round 9
// 87.332 us; speedup vs baseline: 1.0893x; 1.0893x over previous
//
#include <hip/hip_runtime.h>
#include <math.h>

#define NB 8
#define ND 128
#define NT 2048
#define NF 1025
#define NYY 256
#define NXX 256

#define SPEC_BYTES 8396800          /* 8*128*1025*8 */
#define BAND_PART_BYTES 2097152     /* 8*128*256*8 (fp32 bandS) */
#define BANDH_PART_BYTES 1048576    /* 8*128*256*4 (bf16x2 band part) */
#define PART_OFF   1024
#define SPECT_OFF  8192
#define SF_OFF     (SPECT_OFF + SPEC_BYTES)            /* 8,404,992 */
#define BAND_OFF   (SF_OFF + SPEC_BYTES)               /* 16,801,792 */

// ---------------- kernel 1a: per-chunk sums for standardization ----------------
__global__ __launch_bounds__(256) void fk_part_sums(const float* __restrict__ sino,
                                                    double2* __restrict__ part) {
  const int c = blockIdx.x;   // 0..31 chunk
  const int b = blockIdx.y;   // 0..7 batch
  const int tid = threadIdx.x;
  const int chunk = ND * NT / 32;  // 8192
  const float* p = sino + (size_t)b * ND * NT + (size_t)c * chunk;
  double s = 0.0, ss = 0.0;
  for (int i = tid; i < chunk; i += 256) {
    float v = p[i];
    s += (double)v;
    ss += (double)v * (double)v;
  }
  __shared__ double shs[256];
  __shared__ double shq[256];
  shs[tid] = s; shq[tid] = ss;
  __syncthreads();
  for (int o = 128; o > 0; o >>= 1) {
    if (tid < o) { shs[tid] += shs[tid + o]; shq[tid] += shq[tid + o]; }
    __syncthreads();
  }
  if (tid == 0) part[b * 32 + c] = make_double2(shs[0], shq[0]);
}

// ---------------- kernel 1b: finalize 1/sqrt(var+eps) ----------------
__global__ void fk_scale_k(const double2* __restrict__ part, float* __restrict__ scale) {
  int t = threadIdx.x;
  if (t < NB) {
    double s = 0.0, ss = 0.0;
    for (int c = 0; c < 32; ++c) { double2 v = part[t * 32 + c]; s += v.x; ss += v.y; }
    const double n = (double)(ND * NT);
    double mean = s / n;
    double var = ss / n - mean * mean;
    scale[t] = (float)(1.0 / sqrt(var + 1.1920928955078125e-7));
  }
}

// ---------------- kernel 2: real 2048-pt rfft via 1024-pt complex FFT + untangle ----
__global__ __launch_bounds__(256) void fk_tfft(const float* __restrict__ sino,
                                               float2* __restrict__ specT) {
  const int row = blockIdx.x;      // b*ND + d
  const int d = row & (ND - 1);
  const int tid = threadIdx.x;
  __shared__ float2 bufA[1024];
  __shared__ float2 bufB[1024];
  const float ap = (float)(0.5 - 0.5 * cos(6.283185307179586 * (double)d / 127.0));
  const float2* in = (const float2*)(sino + (size_t)row * NT);   // z[n] = x[2n] + i x[2n+1]
  for (int i = tid; i < 1024; i += 256) {
    float2 v = in[i];
    bufA[i] = make_float2(v.x * ap, v.y * ap);
  }
  __syncthreads();
  float2* src = bufA;
  float2* dst = bufB;
  for (int p = 1; p <= 512; p <<= 1) {
    #pragma unroll
    for (int it = 0; it < 2; ++it) {
      int i = tid + it * 256;
      int k = i & (p - 1);
      float2 u = src[i];
      float2 v = src[i + 512];
      float ang = -3.14159265358979323846f * ((float)k / (float)p);
      float sn, cs; __sincosf(ang, &sn, &cs);
      float2 vw = make_float2(v.x * cs - v.y * sn, v.x * sn + v.y * cs);
      int j = ((i - k) << 1) + k;
      dst[j]     = make_float2(u.x + vw.x, u.y + vw.y);
      dst[j + p] = make_float2(u.x - vw.x, u.y - vw.y);
    }
    __syncthreads();
    float2* t = src; src = dst; dst = t;
  }
  // src = Z[0..1023]; untangle to rfft X[0..1024]
  float2* out = specT + (size_t)row * NF;
  for (int k = tid; k < 1024; k += 256) {
    float2 zk = src[k];
    float2 zc = src[(1024 - k) & 1023]; zc.y = -zc.y;          // conj
    float2 xe = make_float2(0.5f * (zk.x + zc.x), 0.5f * (zk.y + zc.y));
    float ax = zk.x - zc.x, ay = zk.y - zc.y;
    float2 xo = make_float2(0.5f * ay, -0.5f * ax);            // (Z - Zc)/(2i)
    float ang = -3.14159265358979323846f * ((float)k / 1024.0f);
    float sn, cs; __sincosf(ang, &sn, &cs);
    out[k] = make_float2(xe.x + cs * xo.x - sn * xo.y,
                         xe.y + cs * xo.y + sn * xo.x);
  }
  if (tid == 0) {
    float2 z0 = src[0];
    out[1024] = make_float2(z0.x - z0.y, 0.0f);
  }
}

// ---------------- kernel 3: detector FFT (128-pt) + prop_mask*fw ----------------
__global__ __launch_bounds__(256) void fk_dfft(const float2* __restrict__ specT,
                                               float2* __restrict__ sf) {
  const int b = blockIdx.y;
  const int f0 = blockIdx.x * 4;
  const int sub = threadIdx.x >> 6;   // 0..3 (which f)
  const int i = threadIdx.x & 63;     // butterfly index
  const int f = f0 + sub;
  const bool valid = (f < NF);
  __shared__ float2 A[4][128];
  __shared__ float2 Bf[4][128];
  if (valid) {
    const float2* col = specT + ((size_t)b * ND) * NF + f;
    A[sub][i]      = col[(size_t)i * NF];
    A[sub][i + 64] = col[(size_t)(i + 64) * NF];
  }
  __syncthreads();
  float2 (*src)[128] = A;
  float2 (*dst)[128] = Bf;
  for (int p = 1; p <= 64; p <<= 1) {
    if (valid) {
      int k = i & (p - 1);
      float2 u = src[sub][i];
      float2 v = src[sub][i + 64];
      float ang = -3.14159265358979323846f * ((float)k / (float)p);
      float sn, cs; __sincosf(ang, &sn, &cs);
      float2 vw = make_float2(v.x * cs - v.y * sn, v.x * sn + v.y * cs);
      int j = ((i - k) << 1) + k;
      dst[sub][j]     = make_float2(u.x + vw.x, u.y + vw.y);
      dst[sub][j + p] = make_float2(u.x - vw.x, u.y - vw.y);
    }
    __syncthreads();
    float2 (*t)[128] = src; src = dst; dst = t;
  }
  if (valid) {
    const float fwv = (f == 0 || f == NF - 1) ? 1.0f : 2.0f;
    double freqd = (double)f / 5.12e-5;
    float omega = (float)(freqd * 6.283185307179586);
    float woc = omega / 1540.0f;
    float woc2 = __fmul_rn(woc, woc);
    #pragma unroll
    for (int h = 0; h < 2; ++h) {
      int kd = i + h * 64;
      int kt = kd < 64 ? kd : kd - 128;
      float kxv = (float)(6.283185307179586 * ((double)kt / 0.0384));
      float kzsq = __fsub_rn(woc2, __fmul_rn(kxv, kxv));
      float m = (kzsq > 0.0f) ? fwv : 0.0f;
      float2 v = src[sub][kd];
      sf[((size_t)(b * ND + kd)) * NF + f] = make_float2(v.x * m, v.y * m);
    }
  }
}

__device__ __forceinline__ unsigned int bf16rne(float x) {
  unsigned int u = __float_as_uint(x);
  return (u + 0x7fffu + ((u >> 16) & 1u)) >> 16;
}

// ---------------- kernel 4: band_h[part][b][d][y] (bf16x2) = sum_f sf*exp(i*kz*y) ----
// Wave w owns d = dblk*4+w; thread owns 4 CONSECUTIVE y (4l..4l+3).
// Per f: 1 lane-varying sincos + 1 uniform delta sincos + 3 cmuls give all 4 phases.
__global__ __launch_bounds__(256, 3) void fk_band(const float2* __restrict__ sf,
                                                  unsigned int* __restrict__ bandh,
                                                  int flen_base, int fpad) {
  const int dblk = blockIdx.x;   // 0..31
  const int part = blockIdx.y;   // 0..FPART-1
  const int f0 = part * flen_base;
  const int flen = min(flen_base, NF - f0);
  const int tid = threadIdx.x;
  const int w = tid >> 6, l = tid & 63;
  const int d = dblk * 4 + w;

  extern __shared__ float lds[];
  float2* sfs = (float2*)lds;            // [32 rows][fpad]  row = w*8+b
  float*  kzs = lds + 64 * fpad;         // [4][fpad]

  // stage sf rows (8-thread runs per row)
  {
    const int row = tid >> 3;            // 0..31
    const int wr = row >> 3, br = row & 7;
    const int dr = dblk * 4 + wr;
    const float2* srcp = sf + ((size_t)(br * ND + dr)) * NF + f0;
    for (int ff = tid & 7; ff < fpad; ff += 8)
      sfs[row * fpad + ff] = (ff < flen) ? srcp[ff] : make_float2(0.f, 0.f);
  }
  // stage kz per wave-d
  for (int e = tid; e < 4 * fpad; e += 256) {
    const int wk = e / fpad, ff = e - wk * fpad;
    float kzv = 0.f;
    if (ff < flen) {
      int dk = dblk * 4 + wk;
      int kt = dk < 64 ? dk : dk - 128;
      float kxv = (float)(6.283185307179586 * ((double)kt / 0.0384));
      float kx2 = __fmul_rn(kxv, kxv);
      int f = f0 + ff;
      double freqd = (double)f / 5.12e-5;
      float omega = (float)(freqd * 6.283185307179586);
      float woc = omega / 1540.0f;
      float kzsq = __fsub_rn(__fmul_rn(woc, woc), kx2);
      kzv = (kzsq > 0.0f) ? sqrtf(kzsq) : 0.0f;
    }
    kzs[e] = kzv;
  }
  __syncthreads();

  const float y0 = (float)(1.0e-3 + (double)(4 * l) * 1.5e-4);
  const float dy = 1.5e-4f;

  float2 acc[8][4];
  #pragma unroll
  for (int b = 0; b < 8; ++b)
    #pragma unroll
    for (int i = 0; i < 4; ++i) acc[b][i] = make_float2(0.f, 0.f);

  const float* kzw = kzs + w * fpad;
  const float2* rows = sfs + (w * 8) * fpad;

  #pragma unroll 2
  for (int ff = 0; ff < fpad; ++ff) {
    const float kz = kzw[ff];                      // uniform b32 broadcast
    float s0, c0, sd, cd;
    __sincosf(kz * y0, &s0, &c0);
    __sincosf(kz * dy, &sd, &cd);                  // uniform across lanes
    float2 ph[4];
    ph[0] = make_float2(c0, s0);
    #pragma unroll
    for (int i = 0; i < 3; ++i)
      ph[i + 1] = make_float2(ph[i].x * cd - ph[i].y * sd,
                              ph[i].x * sd + ph[i].y * cd);
    #pragma unroll
    for (int b = 0; b < 8; ++b) {
      float2 p = rows[b * fpad + ff];              // uniform broadcast b64
      #pragma unroll
      for (int i = 0; i < 4; ++i) {
        acc[b][i].x = fmaf(p.x, ph[i].x, fmaf(-p.y, ph[i].y, acc[b][i].x));
        acc[b][i].y = fmaf(p.x, ph[i].y, fmaf( p.y, ph[i].x, acc[b][i].y));
      }
    }
  }

  unsigned int* outp = bandh + (size_t)part * (NB * ND * NYY);
  #pragma unroll
  for (int b = 0; b < 8; ++b) {
    uint4 pk;
    pk.x = bf16rne(acc[b][0].x) | (bf16rne(acc[b][0].y) << 16);
    pk.y = bf16rne(acc[b][1].x) | (bf16rne(acc[b][1].y) << 16);
    pk.z = bf16rne(acc[b][2].x) | (bf16rne(acc[b][2].y) << 16);
    pk.w = bf16rne(acc[b][3].x) | (bf16rne(acc[b][3].y) << 16);
    ((uint4*)(outp + ((size_t)(b * ND + d)) * NYY))[l] = pk;   // 16B/lane coalesced
  }
}

// ---------------- kernel 4b: bandS[b][d][y] (fp32) = sum_part band_h ----------------
__global__ __launch_bounds__(256) void fk_sum(const unsigned int* __restrict__ bandh,
                                              float2* __restrict__ bandS, int nparts) {
  const int n = blockIdx.x * 256 + threadIdx.x;   // [b][d][y], coalesced both sides
  float sx = 0.f, sy = 0.f;
  for (int p = 0; p < nparts; ++p) {
    unsigned int u = bandh[(size_t)p * (NB * ND * NYY) + n];
    sx += __uint_as_float(u << 16);
    sy += __uint_as_float(u & 0xffff0000u);
  }
  bandS[n] = make_float2(sx, sy);
}

// ---------------- kernel 5: lateral transform as 256-pt inverse FFT + magnitude ----
__global__ __launch_bounds__(256) void fk_img(const float2* __restrict__ bandS,
                                              const float* __restrict__ scale,
                                              float* __restrict__ out, float inv_norm) {
  const int y = blockIdx.x;
  const int b = blockIdx.y;
  const int tid = threadIdx.x;
  __shared__ float2 A[256];
  __shared__ float2 Bb[256];
  {
    float2 v = make_float2(0.f, 0.f);
    if (tid < 64)        v = bandS[((size_t)(b * ND + tid)) * NYY + y];        // bin d
    else if (tid >= 192) v = bandS[((size_t)(b * ND + tid - 128)) * NYY + y];  // bin d+128
    A[tid] = v;
  }
  __syncthreads();
  float2* src = A;
  float2* dst = Bb;
  for (int p = 1; p <= 128; p <<= 1) {
    if (tid < 128) {
      int i = tid;
      int k = i & (p - 1);
      float2 u = src[i];
      float2 v = src[i + 128];
      float ang = 3.14159265358979323846f * ((float)k / (float)p);   // +: inverse
      float sn, cs; __sincosf(ang, &sn, &cs);
      float2 vw = make_float2(v.x * cs - v.y * sn, v.x * sn + v.y * cs);
      int j = ((i - k) << 1) + k;
      dst[j]     = make_float2(u.x + vw.x, u.y + vw.y);
      dst[j + p] = make_float2(u.x - vw.x, u.y - vw.y);
    }
    __syncthreads();
    float2* t = src; src = dst; dst = t;
  }
  float2 r = src[tid];
  float mag = sqrtf(r.x * r.x + r.y * r.y);
  out[((size_t)b * NYY + y) * NXX + tid] = mag * scale[b] * inv_norm;
}

extern "C" void kernel_launch(void* const* d_in, const int* in_sizes, int n_in,
                              void* d_out, int out_size, void* d_ws, size_t ws_size,
                              hipStream_t stream) {
  const float* sino = (const float*)d_in[0];
  float* out = (float*)d_out;
  char* ws = (char*)d_ws;

  float*        scale = (float*)(ws + 0);
  double2*      part  = (double2*)(ws + PART_OFF);
  float2*       specT = (float2*)(ws + SPECT_OFF);
  float2*       sf    = (float2*)(ws + SF_OFF);
  unsigned int* bandh = (unsigned int*)(ws + BAND_OFF);

  // f-partition tier from ws_size (deterministic)
  int FPART = 8;
  if (ws_size >= (size_t)BAND_OFF + 24u * BANDH_PART_BYTES + BAND_PART_BYTES) FPART = 24;
  const int flen_base = (NF + FPART - 1) / FPART;     // 43 / 129
  const int fpad = (flen_base + 1) & ~1;              // 44 / 130
  const size_t band_lds = (size_t)fpad * 272;         // 32*8B + 4*4B per ff
  float2* bandS = (float2*)(ws + BAND_OFF + (size_t)FPART * BANDH_PART_BYTES);

  double apod_sum = 0.0;
  for (int n = 0; n < ND; ++n) apod_sum += 0.5 - 0.5 * cos(6.283185307179586 * (double)n / 127.0);
  const float inv_norm = (float)(1.0 / (apod_sum * 2048.0));

  fk_part_sums<<<dim3(32, NB), 256, 0, stream>>>(sino, part);
  fk_scale_k <<<1, 64, 0, stream>>>(part, scale);
  fk_tfft    <<<NB * ND, 256, 0, stream>>>(sino, specT);
  fk_dfft    <<<dim3((NF + 3) / 4, NB), 256, 0, stream>>>(specT, sf);
  fk_band    <<<dim3(32, FPART), 256, band_lds, stream>>>(sf, bandh, flen_base, fpad);
  fk_sum     <<<NB * ND * NYY / 256, 256, 0, stream>>>(bandh, bandS, FPART);
  fk_img     <<<dim3(NYY, NB), 256, 0, stream>>>(bandS, scale, out, inv_norm);
}

// Round 10
// 76.647 us; speedup vs baseline: 1.2412x; 1.1394x over previous
//
#include <hip/hip_runtime.h>
#include <math.h>

#define NB 8
#define ND 128
#define NT 2048
#define NF 1025
#define NYY 256
#define NXX 256

#define SPEC_BYTES 8396800          /* 8*128*1025*8 */
#define BAND_PART_BYTES 2097152     /* 8*128*256*8 (fp32 bandS) */
#define BANDH_PART_BYTES 1048576    /* 8*128*256*4 (bf16x2 band part) */
#define ROWSTAT_OFF 0               /* 1024 float2 = 8KB */
#define SPECT_OFF  8192
#define SF_OFF     (SPECT_OFF + SPEC_BYTES)            /* 8,404,992 */
#define BAND_OFF   (SF_OFF + SPEC_BYTES)               /* 16,801,792 */

// ---------------- kernel 1: real 2048-pt rfft via 1024-pt complex FFT + untangle ----
// Also emits per-row raw (sum, sumsq) for the standardization scale (folded into fk_img).
__global__ __launch_bounds__(256) void fk_tfft(const float* __restrict__ sino,
                                               float2* __restrict__ specT,
                                               float2* __restrict__ rowstat) {
  const int row = blockIdx.x;      // b*ND + d
  const int d = row & (ND - 1);
  const int tid = threadIdx.x;
  __shared__ float2 bufA[1024];
  __shared__ float2 bufB[1024];
  __shared__ float2 wsum[4];
  const float ap = (float)(0.5 - 0.5 * cos(6.283185307179586 * (double)d / 127.0));
  const float2* in = (const float2*)(sino + (size_t)row * NT);   // z[n] = x[2n] + i x[2n+1]
  float s = 0.f, q = 0.f;
  for (int i = tid; i < 1024; i += 256) {
    float2 v = in[i];
    s += v.x + v.y;
    q += v.x * v.x + v.y * v.y;
    bufA[i] = make_float2(v.x * ap, v.y * ap);
  }
  #pragma unroll
  for (int o = 32; o > 0; o >>= 1) {
    s += __shfl_down(s, o);
    q += __shfl_down(q, o);
  }
  if ((tid & 63) == 0) wsum[tid >> 6] = make_float2(s, q);
  __syncthreads();
  if (tid == 0) {
    rowstat[row] = make_float2(wsum[0].x + wsum[1].x + wsum[2].x + wsum[3].x,
                               wsum[0].y + wsum[1].y + wsum[2].y + wsum[3].y);
  }
  float2* src = bufA;
  float2* dst = bufB;
  for (int p = 1; p <= 512; p <<= 1) {
    #pragma unroll
    for (int it = 0; it < 2; ++it) {
      int i = tid + it * 256;
      int k = i & (p - 1);
      float2 u = src[i];
      float2 v = src[i + 512];
      float ang = -3.14159265358979323846f * ((float)k / (float)p);
      float sn, cs; __sincosf(ang, &sn, &cs);
      float2 vw = make_float2(v.x * cs - v.y * sn, v.x * sn + v.y * cs);
      int j = ((i - k) << 1) + k;
      dst[j]     = make_float2(u.x + vw.x, u.y + vw.y);
      dst[j + p] = make_float2(u.x - vw.x, u.y - vw.y);
    }
    __syncthreads();
    float2* t = src; src = dst; dst = t;
  }
  // src = Z[0..1023]; untangle to rfft X[0..1024]
  float2* out = specT + (size_t)row * NF;
  for (int k = tid; k < 1024; k += 256) {
    float2 zk = src[k];
    float2 zc = src[(1024 - k) & 1023]; zc.y = -zc.y;          // conj
    float2 xe = make_float2(0.5f * (zk.x + zc.x), 0.5f * (zk.y + zc.y));
    float ax = zk.x - zc.x, ay = zk.y - zc.y;
    float2 xo = make_float2(0.5f * ay, -0.5f * ax);            // (Z - Zc)/(2i)
    float ang = -3.14159265358979323846f * ((float)k / 1024.0f);
    float sn, cs; __sincosf(ang, &sn, &cs);
    out[k] = make_float2(xe.x + cs * xo.x - sn * xo.y,
                         xe.y + cs * xo.y + sn * xo.x);
  }
  if (tid == 0) {
    float2 z0 = src[0];
    out[1024] = make_float2(z0.x - z0.y, 0.0f);
  }
}

// ---------------- kernel 2: detector FFT (128-pt) + prop_mask*fw ----------------
__global__ __launch_bounds__(256) void fk_dfft(const float2* __restrict__ specT,
                                               float2* __restrict__ sf) {
  const int b = blockIdx.y;
  const int f0 = blockIdx.x * 4;
  const int sub = threadIdx.x >> 6;   // 0..3 (which f)
  const int i = threadIdx.x & 63;     // butterfly index
  const int f = f0 + sub;
  const bool valid = (f < NF);
  __shared__ float2 A[4][128];
  __shared__ float2 Bf[4][128];
  if (valid) {
    const float2* col = specT + ((size_t)b * ND) * NF + f;
    A[sub][i]      = col[(size_t)i * NF];
    A[sub][i + 64] = col[(size_t)(i + 64) * NF];
  }
  __syncthreads();
  float2 (*src)[128] = A;
  float2 (*dst)[128] = Bf;
  for (int p = 1; p <= 64; p <<= 1) {
    if (valid) {
      int k = i & (p - 1);
      float2 u = src[sub][i];
      float2 v = src[sub][i + 64];
      float ang = -3.14159265358979323846f * ((float)k / (float)p);
      float sn, cs; __sincosf(ang, &sn, &cs);
      float2 vw = make_float2(v.x * cs - v.y * sn, v.x * sn + v.y * cs);
      int j = ((i - k) << 1) + k;
      dst[sub][j]     = make_float2(u.x + vw.x, u.y + vw.y);
      dst[sub][j + p] = make_float2(u.x - vw.x, u.y - vw.y);
    }
    __syncthreads();
    float2 (*t)[128] = src; src = dst; dst = t;
  }
  if (valid) {
    const float fwv = (f == 0 || f == NF - 1) ? 1.0f : 2.0f;
    double freqd = (double)f / 5.12e-5;
    float omega = (float)(freqd * 6.283185307179586);
    float woc = omega / 1540.0f;
    float woc2 = __fmul_rn(woc, woc);
    #pragma unroll
    for (int h = 0; h < 2; ++h) {
      int kd = i + h * 64;
      int kt = kd < 64 ? kd : kd - 128;
      float kxv = (float)(6.283185307179586 * ((double)kt / 0.0384));
      float kzsq = __fsub_rn(woc2, __fmul_rn(kxv, kxv));
      float m = (kzsq > 0.0f) ? fwv : 0.0f;
      float2 v = src[sub][kd];
      sf[((size_t)(b * ND + kd)) * NF + f] = make_float2(v.x * m, v.y * m);
    }
  }
}

__device__ __forceinline__ unsigned int bf16rne(float x) {
  unsigned int u = __float_as_uint(x);
  return (u + 0x7fffu + ((u >> 16) & 1u)) >> 16;
}

// ---------------- kernel 3: band_h[part][b][d][y] (bf16x2) = sum_f sf*exp(i*kz*y) ----
// Wave w owns d = dblk*4+w; thread owns 4 consecutive y. Staging precomputes
// {kz, cos(kz*dy), sin(kz*dy)} so the inner loop has ONE sincos + 3 cmuls.
__global__ __launch_bounds__(256, 3) void fk_band(const float2* __restrict__ sf,
                                                  unsigned int* __restrict__ bandh,
                                                  int flen_base, int fpad) {
  const int dblk = blockIdx.x;   // 0..31
  const int part = blockIdx.y;   // 0..FPART-1
  const int f0 = part * flen_base;
  const int flen = min(flen_base, NF - f0);
  const int tid = threadIdx.x;
  const int w = tid >> 6, l = tid & 63;
  const int d = dblk * 4 + w;

  extern __shared__ float lds[];
  float2* sfs = (float2*)lds;                  // [32 rows][fpad]  row = w*8+b
  float4* kcs = (float4*)(lds + 64 * fpad);    // [4][fpad] {kz, cd, sd, -}

  // stage sf rows (8-thread runs per row)
  {
    const int row = tid >> 3;            // 0..31
    const int wr = row >> 3, br = row & 7;
    const int dr = dblk * 4 + wr;
    const float2* srcp = sf + ((size_t)(br * ND + dr)) * NF + f0;
    for (int ff = tid & 7; ff < fpad; ff += 8)
      sfs[row * fpad + ff] = (ff < flen) ? srcp[ff] : make_float2(0.f, 0.f);
  }
  // stage kz + uniform delta-phase per wave-d
  for (int e = tid; e < 4 * fpad; e += 256) {
    const int wk = e / fpad, ff = e - wk * fpad;
    float kzv = 0.f;
    if (ff < flen) {
      int dk = dblk * 4 + wk;
      int kt = dk < 64 ? dk : dk - 128;
      float kxv = (float)(6.283185307179586 * ((double)kt / 0.0384));
      float kx2 = __fmul_rn(kxv, kxv);
      int f = f0 + ff;
      double freqd = (double)f / 5.12e-5;
      float omega = (float)(freqd * 6.283185307179586);
      float woc = omega / 1540.0f;
      float kzsq = __fsub_rn(__fmul_rn(woc, woc), kx2);
      kzv = (kzsq > 0.0f) ? sqrtf(kzsq) : 0.0f;
    }
    float sd, cd;
    __sincosf(kzv * 1.5e-4f, &sd, &cd);
    kcs[e] = make_float4(kzv, cd, sd, 0.f);
  }
  __syncthreads();

  const float y0 = (float)(1.0e-3 + (double)(4 * l) * 1.5e-4);

  float2 acc[8][4];
  #pragma unroll
  for (int b = 0; b < 8; ++b)
    #pragma unroll
    for (int i = 0; i < 4; ++i) acc[b][i] = make_float2(0.f, 0.f);

  const float4* kcw = kcs + w * fpad;
  const float2* rows = sfs + (w * 8) * fpad;

  #pragma unroll 2
  for (int ff = 0; ff < fpad; ++ff) {
    const float4 k4 = kcw[ff];                     // uniform b128 broadcast
    float s0, c0;
    __sincosf(k4.x * y0, &s0, &c0);
    float2 ph[4];
    ph[0] = make_float2(c0, s0);
    #pragma unroll
    for (int i = 0; i < 3; ++i)
      ph[i + 1] = make_float2(ph[i].x * k4.y - ph[i].y * k4.z,
                              ph[i].x * k4.z + ph[i].y * k4.y);
    #pragma unroll
    for (int b = 0; b < 8; ++b) {
      float2 p = rows[b * fpad + ff];              // uniform broadcast b64
      #pragma unroll
      for (int i = 0; i < 4; ++i) {
        acc[b][i].x = fmaf(p.x, ph[i].x, fmaf(-p.y, ph[i].y, acc[b][i].x));
        acc[b][i].y = fmaf(p.x, ph[i].y, fmaf( p.y, ph[i].x, acc[b][i].y));
      }
    }
  }

  unsigned int* outp = bandh + (size_t)part * (NB * ND * NYY);
  #pragma unroll
  for (int b = 0; b < 8; ++b) {
    uint4 pk;
    pk.x = bf16rne(acc[b][0].x) | (bf16rne(acc[b][0].y) << 16);
    pk.y = bf16rne(acc[b][1].x) | (bf16rne(acc[b][1].y) << 16);
    pk.z = bf16rne(acc[b][2].x) | (bf16rne(acc[b][2].y) << 16);
    pk.w = bf16rne(acc[b][3].x) | (bf16rne(acc[b][3].y) << 16);
    ((uint4*)(outp + ((size_t)(b * ND + d)) * NYY))[l] = pk;   // 16B/lane coalesced
  }
}

// ---------------- kernel 4: bandS[b][d][y] (fp32) = sum_part band_h ----------------
__global__ __launch_bounds__(256) void fk_sum(const unsigned int* __restrict__ bandh,
                                              float2* __restrict__ bandS, int nparts) {
  const int n = blockIdx.x * 256 + threadIdx.x;   // [b][d][y], coalesced both sides
  float sx = 0.f, sy = 0.f;
  for (int p = 0; p < nparts; ++p) {
    unsigned int u = bandh[(size_t)p * (NB * ND * NYY) + n];
    sx += __uint_as_float(u << 16);
    sy += __uint_as_float(u & 0xffff0000u);
  }
  bandS[n] = make_float2(sx, sy);
}

// ---------------- kernel 5: lateral 256-pt inverse FFT + magnitude + scale ----------
__global__ __launch_bounds__(256) void fk_img(const float2* __restrict__ bandS,
                                              const float2* __restrict__ rowstat,
                                              float* __restrict__ out, float inv_norm) {
  const int y = blockIdx.x;
  const int b = blockIdx.y;
  const int tid = threadIdx.x;
  __shared__ float2 A[256];
  __shared__ float2 Bb[256];
  __shared__ float2 spart[2];
  float2 myrs = make_float2(0.f, 0.f);
  if (tid < 128) myrs = rowstat[b * ND + tid];
  {
    float2 v = make_float2(0.f, 0.f);
    if (tid < 64)        v = bandS[((size_t)(b * ND + tid)) * NYY + y];        // bin d
    else if (tid >= 192) v = bandS[((size_t)(b * ND + tid - 128)) * NYY + y];  // bin d+128
    A[tid] = v;
  }
  {
    float s = myrs.x, q = myrs.y;
    #pragma unroll
    for (int o = 32; o > 0; o >>= 1) {
      s += __shfl_down(s, o);
      q += __shfl_down(q, o);
    }
    if (tid < 128 && (tid & 63) == 0) spart[tid >> 6] = make_float2(s, q);
  }
  __syncthreads();
  const float nInv = 1.0f / 262144.0f;
  float ssum = spart[0].x + spart[1].x;
  float qsum = spart[0].y + spart[1].y;
  float mean = ssum * nInv;
  float var = qsum * nInv - mean * mean;
  float scl = 1.0f / sqrtf(var + 1.1920928955078125e-7f);

  float2* src = A;
  float2* dst = Bb;
  for (int p = 1; p <= 128; p <<= 1) {
    if (tid < 128) {
      int i = tid;
      int k = i & (p - 1);
      float2 u = src[i];
      float2 v = src[i + 128];
      float ang = 3.14159265358979323846f * ((float)k / (float)p);   // +: inverse
      float sn, cs; __sincosf(ang, &sn, &cs);
      float2 vw = make_float2(v.x * cs - v.y * sn, v.x * sn + v.y * cs);
      int j = ((i - k) << 1) + k;
      dst[j]     = make_float2(u.x + vw.x, u.y + vw.y);
      dst[j + p] = make_float2(u.x - vw.x, u.y - vw.y);
    }
    __syncthreads();
    float2* t = src; src = dst; dst = t;
  }
  float2 r = src[tid];
  float mag = sqrtf(r.x * r.x + r.y * r.y);
  out[((size_t)b * NYY + y) * NXX + tid] = mag * scl * inv_norm;
}

extern "C" void kernel_launch(void* const* d_in, const int* in_sizes, int n_in,
                              void* d_out, int out_size, void* d_ws, size_t ws_size,
                              hipStream_t stream) {
  const float* sino = (const float*)d_in[0];
  float* out = (float*)d_out;
  char* ws = (char*)d_ws;

  float2*       rowstat = (float2*)(ws + ROWSTAT_OFF);
  float2*       specT   = (float2*)(ws + SPECT_OFF);
  float2*       sf      = (float2*)(ws + SF_OFF);
  unsigned int* bandh   = (unsigned int*)(ws + BAND_OFF);

  // f-partition tier from ws_size (deterministic)
  int FPART = 8;
  if (ws_size >= (size_t)BAND_OFF + 24u * BANDH_PART_BYTES + BAND_PART_BYTES) FPART = 24;
  const int flen_base = (NF + FPART - 1) / FPART;     // 43 / 129
  const int fpad = (flen_base + 1) & ~1;              // 44 / 130
  const size_t band_lds = (size_t)fpad * 320;         // 32*8B + 16B per ff
  float2* bandS = (float2*)(ws + BAND_OFF + (size_t)FPART * BANDH_PART_BYTES);

  double apod_sum = 0.0;
  for (int n = 0; n < ND; ++n) apod_sum += 0.5 - 0.5 * cos(6.283185307179586 * (double)n / 127.0);
  const float inv_norm = (float)(1.0 / (apod_sum * 2048.0));

  fk_tfft<<<NB * ND, 256, 0, stream>>>(sino, specT, rowstat);
  fk_dfft<<<dim3((NF + 3) / 4, NB), 256, 0, stream>>>(specT, sf);
  fk_band<<<dim3(32, FPART), 256, band_lds, stream>>>(sf, bandh, flen_base, fpad);
  fk_sum <<<NB * ND * NYY / 256, 256, 0, stream>>>(bandh, bandS, FPART);
  fk_img <<<dim3(NYY, NB), 256, 0, stream>>>(bandS, rowstat, out, inv_norm);
}